// Round 5
// baseline (1908.354 us; speedup 1.0000x reference)
//
#include <hip/hip_runtime.h>

#define B_TOTAL 8192
#define T_FULL  100
#define XD      256
#define T0      30
#define TW      70      // time window length (30:100)
#define KS      50      // conv kernel size
#define NT      21      // TW - KS + 1 output positions
#define YOUT    300     // Y_DIM * 50
#define NB      8       // batches per block

// SSA register storage: ext_vector values are never allocas (unlike float
// arrays, which SROA fails to promote here -> 1.9 GB scratch in rounds 2-4).
typedef float f16v __attribute__((ext_vector_type(16)));
typedef float f8v  __attribute__((ext_vector_type(8)));

__global__ __launch_bounds__(256)
void tiancnn_fused(const float* __restrict__ seq,
                   const float* __restrict__ conv_w,
                   const float* __restrict__ fc_w,
                   float* __restrict__ out) {
    __shared__ float feat[NB][XD];

    const int f  = threadIdx.x;          // feature index 0..255
    const int b0 = blockIdx.x * NB;
    const float* wp = conv_w + f * KS;

#pragma unroll 1
    for (int nb = 0; nb < NB; ++nb) {
        const float* xp = seq + ((size_t)(b0 + nb) * T_FULL + T0) * XD + f;

        // 21 accumulators in vector slots 0..20
        f16v a0; f8v a1;
#pragma unroll
        for (int t = 0; t < 16; ++t) a0[t] = 0.f;
#pragma unroll
        for (int t = 0; t < 8; ++t)  a1[t] = 0.f;

        // 50 weight slots; slot k is written at j==k and last read at
        // j==k+20, so only ~21 are live at any point (sliding window).
        f16v w0v, w1v, w2v; f8v w3v;

        // Streaming conv: each x_j loaded exactly once, feeds <=21 FMAs.
#pragma unroll
        for (int j = 0; j < TW; ++j) {
            const float x = xp[(size_t)j * XD];   // 64 lanes = 256B contiguous
            if (j < KS) {
                const float wv = wp[j];
                if      (j < 16) w0v[j]      = wv;
                else if (j < 32) w1v[j - 16] = wv;
                else if (j < 48) w2v[j - 32] = wv;
                else             w3v[j - 48] = wv;
            }
#pragma unroll
            for (int t = 0; t < NT; ++t) {
                const int k = j - t;               // constant after unroll
                if (k >= 0 && k < KS) {
                    const float wk = (k < 16) ? w0v[k]
                                   : (k < 32) ? w1v[k - 16]
                                   : (k < 48) ? w2v[k - 32]
                                   :            w3v[k - 48];
                    float a = (t < 16) ? a0[t] : a1[t - 16];
                    a = fmaf(x, wk, a);
                    if (t < 16) a0[t] = a; else a1[t - 16] = a;
                }
            }
        }

        // max(relu(y)) == max(0, max_t y[t])
        float m = 0.f;
#pragma unroll
        for (int t = 0; t < 16; ++t) m = fmaxf(m, a0[t]);
#pragma unroll
        for (int t = 0; t < NT - 16; ++t) m = fmaxf(m, a1[t]);
        feat[nb][f] = m;
    }
    __syncthreads();

    // ---- FC: out[b0+nb][o] = dot(feat[nb], fc_w[o]) ----
    for (int idx = threadIdx.x; idx < NB * YOUT; idx += 256) {
        const int nb = idx / YOUT;
        const int o  = idx - nb * YOUT;
        const float4* wrow = reinterpret_cast<const float4*>(fc_w + (size_t)o * XD);
        const float*  fv   = feat[nb];
        float acc = 0.f;
#pragma unroll
        for (int q = 0; q < XD / 4; ++q) {
            const float4 wv = wrow[q];
            acc = fmaf(wv.x, fv[4 * q + 0], acc);
            acc = fmaf(wv.y, fv[4 * q + 1], acc);
            acc = fmaf(wv.z, fv[4 * q + 2], acc);
            acc = fmaf(wv.w, fv[4 * q + 3], acc);
        }
        out[(size_t)(b0 + nb) * YOUT + o] = acc;
    }
}

extern "C" void kernel_launch(void* const* d_in, const int* in_sizes, int n_in,
                              void* d_out, int out_size, void* d_ws, size_t ws_size,
                              hipStream_t stream) {
    const float* seq    = (const float*)d_in[0];
    const float* conv_w = (const float*)d_in[1];
    const float* fc_w   = (const float*)d_in[2];
    float*       out    = (float*)d_out;

    tiancnn_fused<<<dim3(B_TOTAL / NB), dim3(256), 0, stream>>>(seq, conv_w, fc_w, out);
}

// Round 6
// 273.076 us; speedup vs baseline: 6.9884x; 6.9884x over previous
//
#include <hip/hip_runtime.h>

#define B_TOTAL 8192
#define T_FULL  100
#define XD      256
#define T0      30
#define TW      70      // time window length (30:100)
#define KS      50      // conv kernel size
#define NT      21      // TW - KS + 1 output positions
#define YOUT    300     // Y_DIM * 50

// ---------------- named-scalar conv machinery (no arrays, no allocas) -------

#define LOADX(K0) \
  x0 =xp[(K0+ 0)*XD]; x1 =xp[(K0+ 1)*XD]; x2 =xp[(K0+ 2)*XD]; x3 =xp[(K0+ 3)*XD]; x4 =xp[(K0+ 4)*XD]; \
  x5 =xp[(K0+ 5)*XD]; x6 =xp[(K0+ 6)*XD]; x7 =xp[(K0+ 7)*XD]; x8 =xp[(K0+ 8)*XD]; x9 =xp[(K0+ 9)*XD]; \
  x10=xp[(K0+10)*XD]; x11=xp[(K0+11)*XD]; x12=xp[(K0+12)*XD]; x13=xp[(K0+13)*XD]; x14=xp[(K0+14)*XD]; \
  x15=xp[(K0+15)*XD]; x16=xp[(K0+16)*XD]; x17=xp[(K0+17)*XD]; x18=xp[(K0+18)*XD]; x19=xp[(K0+19)*XD]; \
  x20=xp[(K0+20)*XD]; x21=xp[(K0+21)*XD]; x22=xp[(K0+22)*XD]; x23=xp[(K0+23)*XD]; x24=xp[(K0+24)*XD]; \
  x25=xp[(K0+25)*XD]; x26=xp[(K0+26)*XD]; x27=xp[(K0+27)*XD]; x28=xp[(K0+28)*XD]; x29=xp[(K0+29)*XD];

#define LOADW(K0) \
  w0=wtp[(K0+0)*XD]; w1=wtp[(K0+1)*XD]; w2=wtp[(K0+2)*XD]; w3=wtp[(K0+3)*XD]; w4=wtp[(K0+4)*XD]; \
  w5=wtp[(K0+5)*XD]; w6=wtp[(K0+6)*XD]; w7=wtp[(K0+7)*XD]; w8=wtp[(K0+8)*XD]; w9=wtp[(K0+9)*XD];

#define ROW(A, X0,X1,X2,X3,X4,X5,X6,X7,X8,X9) \
  A=fmaf(X0,w0,A); A=fmaf(X1,w1,A); A=fmaf(X2,w2,A); A=fmaf(X3,w3,A); A=fmaf(X4,w4,A); \
  A=fmaf(X5,w5,A); A=fmaf(X6,w6,A); A=fmaf(X7,w7,A); A=fmaf(X8,w8,A); A=fmaf(X9,w9,A);

#define KBLOCK \
  ROW(a0 , x0 ,x1 ,x2 ,x3 ,x4 ,x5 ,x6 ,x7 ,x8 ,x9 ) \
  ROW(a1 , x1 ,x2 ,x3 ,x4 ,x5 ,x6 ,x7 ,x8 ,x9 ,x10) \
  ROW(a2 , x2 ,x3 ,x4 ,x5 ,x6 ,x7 ,x8 ,x9 ,x10,x11) \
  ROW(a3 , x3 ,x4 ,x5 ,x6 ,x7 ,x8 ,x9 ,x10,x11,x12) \
  ROW(a4 , x4 ,x5 ,x6 ,x7 ,x8 ,x9 ,x10,x11,x12,x13) \
  ROW(a5 , x5 ,x6 ,x7 ,x8 ,x9 ,x10,x11,x12,x13,x14) \
  ROW(a6 , x6 ,x7 ,x8 ,x9 ,x10,x11,x12,x13,x14,x15) \
  ROW(a7 , x7 ,x8 ,x9 ,x10,x11,x12,x13,x14,x15,x16) \
  ROW(a8 , x8 ,x9 ,x10,x11,x12,x13,x14,x15,x16,x17) \
  ROW(a9 , x9 ,x10,x11,x12,x13,x14,x15,x16,x17,x18) \
  ROW(a10, x10,x11,x12,x13,x14,x15,x16,x17,x18,x19) \
  ROW(a11, x11,x12,x13,x14,x15,x16,x17,x18,x19,x20) \
  ROW(a12, x12,x13,x14,x15,x16,x17,x18,x19,x20,x21) \
  ROW(a13, x13,x14,x15,x16,x17,x18,x19,x20,x21,x22) \
  ROW(a14, x14,x15,x16,x17,x18,x19,x20,x21,x22,x23) \
  ROW(a15, x15,x16,x17,x18,x19,x20,x21,x22,x23,x24) \
  ROW(a16, x16,x17,x18,x19,x20,x21,x22,x23,x24,x25) \
  ROW(a17, x17,x18,x19,x20,x21,x22,x23,x24,x25,x26) \
  ROW(a18, x18,x19,x20,x21,x22,x23,x24,x25,x26,x27) \
  ROW(a19, x19,x20,x21,x22,x23,x24,x25,x26,x27,x28) \
  ROW(a20, x20,x21,x22,x23,x24,x25,x26,x27,x28,x29)

// ---- kernel 1: transpose weights into ws (coalesced-read layouts) ----------
__global__ __launch_bounds__(256)
void transpose_w(const float* __restrict__ conv_w, const float* __restrict__ fc_w,
                 float* __restrict__ wt, float* __restrict__ fct) {
    const int i = blockIdx.x * 256 + threadIdx.x;
    if (i < XD * KS) {                 // conv_w[f][k] -> wt[k][f]
        const int f = i / KS;
        const int k = i - f * KS;
        wt[k * XD + f] = conv_w[i];
    }
    if (i < YOUT * XD) {               // fc_w[o][q] -> fct[q][o]
        const int o = i >> 8;
        const int q = i & 255;
        fct[q * YOUT + o] = fc_w[i];
    }
}

// ---- kernel 2: depthwise conv + relu + time-max -> feat --------------------
__global__ __launch_bounds__(256, 4)
void conv_kernel(const float* __restrict__ seq, const float* __restrict__ wt,
                 float* __restrict__ feat) {
    const int f = threadIdx.x;
    const int b = blockIdx.x;
    const float* xp  = seq + ((size_t)b * T_FULL + T0) * XD + f;
    const float* wtp = wt + f;

    float a0=0,a1=0,a2=0,a3=0,a4=0,a5=0,a6=0,a7=0,a8=0,a9=0,a10=0,
          a11=0,a12=0,a13=0,a14=0,a15=0,a16=0,a17=0,a18=0,a19=0,a20=0;
    float x0,x1,x2,x3,x4,x5,x6,x7,x8,x9,x10,x11,x12,x13,x14,
          x15,x16,x17,x18,x19,x20,x21,x22,x23,x24,x25,x26,x27,x28,x29;
    float w0,w1,w2,w3,w4,w5,w6,w7,w8,w9;

    LOADW(0);  LOADX(0);  KBLOCK;
    LOADW(10); LOADX(10); KBLOCK;
    LOADW(20); LOADX(20); KBLOCK;
    LOADW(30); LOADX(30); KBLOCK;
    LOADW(40); LOADX(40); KBLOCK;

    float m = 0.f;   // max(relu) == max(0, max_t)
    m=fmaxf(m,a0 ); m=fmaxf(m,a1 ); m=fmaxf(m,a2 ); m=fmaxf(m,a3 ); m=fmaxf(m,a4 );
    m=fmaxf(m,a5 ); m=fmaxf(m,a6 ); m=fmaxf(m,a7 ); m=fmaxf(m,a8 ); m=fmaxf(m,a9 );
    m=fmaxf(m,a10); m=fmaxf(m,a11); m=fmaxf(m,a12); m=fmaxf(m,a13); m=fmaxf(m,a14);
    m=fmaxf(m,a15); m=fmaxf(m,a16); m=fmaxf(m,a17); m=fmaxf(m,a18); m=fmaxf(m,a19);
    m=fmaxf(m,a20);
    feat[(size_t)b * XD + f] = m;
}

// ---- kernel 3: FC, one thread per output -----------------------------------
__global__ __launch_bounds__(256, 4)
void fc_kernel(const float* __restrict__ feat, const float* __restrict__ fct,
               float* __restrict__ out) {
    const int idx = blockIdx.x * 256 + threadIdx.x;
    if (idx >= B_TOTAL * YOUT) return;
    const int b = idx / YOUT;
    const int o = idx - b * YOUT;
    const float* fv = feat + (size_t)b * XD;

    float c0=0.f, c1=0.f, c2=0.f, c3=0.f;
#pragma unroll
    for (int q = 0; q < XD; q += 4) {
        const float4 xq = *reinterpret_cast<const float4*>(fv + q);  // broadcast
        c0 = fmaf(xq.x, fct[(q+0)*YOUT + o], c0);
        c1 = fmaf(xq.y, fct[(q+1)*YOUT + o], c1);
        c2 = fmaf(xq.z, fct[(q+2)*YOUT + o], c2);
        c3 = fmaf(xq.w, fct[(q+3)*YOUT + o], c3);
    }
    out[idx] = (c0 + c1) + (c2 + c3);
}

extern "C" void kernel_launch(void* const* d_in, const int* in_sizes, int n_in,
                              void* d_out, int out_size, void* d_ws, size_t ws_size,
                              hipStream_t stream) {
    const float* seq    = (const float*)d_in[0];
    const float* conv_w = (const float*)d_in[1];
    const float* fc_w   = (const float*)d_in[2];
    float*       out    = (float*)d_out;

    float* wt   = (float*)d_ws;          // [50][256]  = 51.2 KB
    float* fct  = wt  + XD * KS;         // [256][300] = 307.2 KB
    float* feat = fct + XD * YOUT;       // [8192][256] = 8.39 MB

    transpose_w<<<dim3((YOUT * XD + 255) / 256), dim3(256), 0, stream>>>(conv_w, fc_w, wt, fct);
    conv_kernel<<<dim3(B_TOTAL), dim3(256), 0, stream>>>(seq, wt, feat);
    fc_kernel<<<dim3((B_TOTAL * YOUT + 255) / 256), dim3(256), 0, stream>>>(feat, fct, out);
}